// Round 1
// 306.796 us; speedup vs baseline: 1.1183x; 1.1183x over previous
//
#include <hip/hip_runtime.h>

typedef __bf16 bf16x8 __attribute__((ext_vector_type(8)));
typedef float floatx4 __attribute__((ext_vector_type(4)));
typedef unsigned short us8 __attribute__((ext_vector_type(8)));

__device__ __forceinline__ unsigned short f2bf(float f) {
    union { float f; unsigned int u; } a;
    a.f = f;
    unsigned int u = a.u;
    return (unsigned short)((u + 0x7FFFu + ((u >> 16) & 1u)) >> 16);  // RNE
}

__device__ __forceinline__ void async_copy16(const void* g, void* l) {
    __builtin_amdgcn_global_load_lds(
        (const __attribute__((address_space(1))) unsigned int*)g,
        (__attribute__((address_space(3))) unsigned int*)l,
        16, 0, 0);
}

__device__ __forceinline__ float sigmoidf_fast(float x) {
    return 1.f / (1.f + __expf(-x));
}
__device__ __forceinline__ float tanhf_fast(float x) {
    return 1.f - 2.f / (__expf(2.f * x) + 1.f);   // exact at +-inf
}

// Prep: [x|h] -> Abf [8192,2048] bf16 (identity rows) and [Wx|Wh] -> Wbf
// [4096,2048] bf16 with row permutation
//   out row n' = hg*64 + gate*16 + hl  <-  src row gate*1024 + hg*16 + hl
// (h = hg*16 + hl) so each 16-col MFMA N-fragment is ONE gate: lane l15 holds
// all 4 gates of its h in registers -> no LDS gate exchange in the GEMM.
// 8 elements/thread: 2x float4 load -> one 16B bf16x8 store.
__global__ __launch_bounds__(256) void prep_cat(
        const float* __restrict__ x, const float* __restrict__ h,
        const float* __restrict__ Wx, const float* __restrict__ Wh,
        unsigned short* __restrict__ Abf, unsigned short* __restrict__ Wbf) {
    int T = blockIdx.x * 256 + threadIdx.x;
    size_t e;
    const float* a;
    const float* b;
    unsigned short* o;
    size_t srow;
    if (T < 2097152) {                       // A: 16,777,216 elems / 8
        e = (size_t)T * 8;
        a = x; b = h; o = Abf;
        srow = e >> 11;
    } else {                                 // W: 8,388,608 elems / 8
        e = (size_t)(T - 2097152) * 8;
        a = Wx; b = Wh; o = Wbf;
        int m = (int)(e >> 11);              // permuted (output) row
        int hg = m >> 6, gate = (m >> 4) & 3, hl = m & 15;
        srow = (size_t)(gate * 1024 + hg * 16 + hl);
    }
    int k = (int)(e & 2047);
    const float* src = (k < 1024) ? (a + srow * 1024 + k)
                                  : (b + srow * 1024 + (k - 1024));
    float4 v0 = ((const float4*)src)[0];
    float4 v1 = ((const float4*)src)[1];
    us8 u;
    u[0] = f2bf(v0.x); u[1] = f2bf(v0.y); u[2] = f2bf(v0.z); u[3] = f2bf(v0.w);
    u[4] = f2bf(v1.x); u[5] = f2bf(v1.y); u[6] = f2bf(v1.z); u[7] = f2bf(v1.w);
    *(us8*)(o + e) = u;
}

// Fused GEMM + LSTM, 256x256 tile, BK=64, 8 waves (2M x 4N), 4 phases per
// K-tile with counted vmcnt (never drain to 0 in steady state), XOR-swizzled
// LDS applied via pre-swizzled global_load_lds SOURCE + swizzled ds_read
// (both-sides rule), setprio around MFMA clusters, XCD-bijective block
// swizzle. Epilogue is register-only: acc[i][gate] per lane.
#define NT 32   // K / 64

__global__ __launch_bounds__(512) void gemm_lstm(
        const unsigned short* __restrict__ A,     // [8192,2048] bf16
        const unsigned short* __restrict__ W,     // [4096,2048] bf16, gate-per-16 rows
        const float* __restrict__ bx, const float* __restrict__ bh,
        const float* __restrict__ c1,             // [8192,1024] f32
        float* __restrict__ out) {                // h_new [8192,1024] then c
    // 2 buffers x (A 256x64 + B 256x64) bf16 = 2 x 64KB = 128KB.
    // Each half-tile = 128 rows x 64 k x 2B = 16KB, row stride 128B,
    // 16B chunk swizzle: phys_chunk = logical_chunk ^ (row & 7).
    __shared__ __align__(16) char smem[131072];

    const int tid = threadIdx.x;
    const int lane = tid & 63;
    const int wave = tid >> 6;
    const int wm = wave >> 2;        // 0..1 -> M half (128 rows)
    const int wn = wave & 3;         // 0..3 -> 64-col span
    const int l15 = lane & 15;
    const int quad = lane >> 4;
    const int sw = l15 & 7;          // read-side swizzle (row&7 == l15&7)

    // XCD-bijective swizzle (512 % 8 == 0): 64 consecutive blocks per XCD,
    // n-major so each XCD reuses 2 W-panels (2MB, L2-resident).
    int bid = (int)blockIdx.x;
    int swz = (bid & 7) * 64 + (bid >> 3);
    const int tileM = (swz & 31) * 256;
    const int tileN = (swz >> 5) * 256;

    // Stage one 16KB half-tile: 512 thr x 2 x 16B. LDS dest linear
    // (wave-uniform base + lane*16); swizzle applied on the GLOBAL source.
    auto stage = [&](const unsigned short* __restrict__ G, int grow0, int kt,
                     char* ldsbase) {
#pragma unroll
        for (int r = 0; r < 2; ++r) {
            int rh = r * 64 + (tid >> 3);
            int kc = (tid & 7) ^ (rh & 7);
            const unsigned short* src = G + (size_t)(grow0 + rh) * 2048 + kt + kc * 8;
            async_copy16(src, ldsbase + r * 8192 + wave * 1024);
        }
    };

    char* b0 = smem;
    char* b1 = smem + 65536;

    // Prologue: A(0), B(0), B(1); leave B(1) in flight (vmcnt(4)).
    stage(A, tileM,        0, b0);
    stage(A, tileM + 128,  0, b0 + 16384);
    stage(W, tileN,        0, b0 + 32768);
    stage(W, tileN + 128,  0, b0 + 49152);
    stage(W, tileN,       64, b1 + 32768);
    stage(W, tileN + 128, 64, b1 + 49152);
    asm volatile("s_waitcnt vmcnt(4)" ::: "memory");
    __builtin_amdgcn_s_barrier();

    floatx4 acc[8][4] = {};
    bf16x8 af[4][2];
    bf16x8 bfr[4][2];

    for (int t = 0; t < NT; ++t) {
        char* cur = smem + (t & 1) * 65536;
        char* nxt = smem + ((t + 1) & 1) * 65536;
        const char* Aw = cur + wm * 16384;                  // this wave's A half
        const char* Bw = cur + 32768 + (wn >> 1) * 16384;   // this wave's B half
        const int br0 = (wn & 1) * 64;

        // ---- phase 1: quadrant (0,0).  Stage A-h0(t+1) -> nxt. ----
#pragma unroll
        for (int i = 0; i < 4; ++i)
#pragma unroll
            for (int ks = 0; ks < 2; ++ks)
                af[i][ks] = *(const bf16x8*)(Aw + (i * 16 + l15) * 128 + (((ks * 4 + quad) ^ sw) * 16));
#pragma unroll
        for (int j = 0; j < 2; ++j)
#pragma unroll
            for (int ks = 0; ks < 2; ++ks)
                bfr[j][ks] = *(const bf16x8*)(Bw + (br0 + j * 16 + l15) * 128 + (((ks * 4 + quad) ^ sw) * 16));
        if (t + 1 < NT) stage(A, tileM, (t + 1) * 64, nxt);
        __builtin_amdgcn_sched_barrier(0);
        __builtin_amdgcn_s_barrier();
        asm volatile("s_waitcnt lgkmcnt(0)" ::: "memory");
        __builtin_amdgcn_sched_barrier(0);
        __builtin_amdgcn_s_setprio(1);
#pragma unroll
        for (int i = 0; i < 4; ++i)
#pragma unroll
            for (int j = 0; j < 2; ++j)
#pragma unroll
                for (int ks = 0; ks < 2; ++ks)
                    acc[i][j] = __builtin_amdgcn_mfma_f32_16x16x32_bf16(af[i][ks], bfr[j][ks], acc[i][j], 0, 0, 0);
        __builtin_amdgcn_s_setprio(0);
        __builtin_amdgcn_s_barrier();

        // ---- phase 2: quadrant (0,1).  Stage A-h1(t+1) -> nxt. ----
#pragma unroll
        for (int j = 0; j < 2; ++j)
#pragma unroll
            for (int ks = 0; ks < 2; ++ks)
                bfr[2 + j][ks] = *(const bf16x8*)(Bw + (br0 + (2 + j) * 16 + l15) * 128 + (((ks * 4 + quad) ^ sw) * 16));
        if (t + 1 < NT) stage(A, tileM + 128, (t + 1) * 64, nxt + 16384);
        __builtin_amdgcn_sched_barrier(0);
        __builtin_amdgcn_s_barrier();
        asm volatile("s_waitcnt lgkmcnt(0)" ::: "memory");
        __builtin_amdgcn_sched_barrier(0);
        __builtin_amdgcn_s_setprio(1);
#pragma unroll
        for (int i = 0; i < 4; ++i)
#pragma unroll
            for (int j = 0; j < 2; ++j)
#pragma unroll
                for (int ks = 0; ks < 2; ++ks)
                    acc[i][2 + j] = __builtin_amdgcn_mfma_f32_16x16x32_bf16(af[i][ks], bfr[2 + j][ks], acc[i][2 + j], 0, 0, 0);
        __builtin_amdgcn_s_setprio(0);
        __builtin_amdgcn_s_barrier();

        // ---- phase 3: quadrant (1,1).  Stage B-h0(t+2) -> cur (freed ph2). ----
#pragma unroll
        for (int i = 0; i < 4; ++i)
#pragma unroll
            for (int ks = 0; ks < 2; ++ks)
                af[i][ks] = *(const bf16x8*)(Aw + (64 + i * 16 + l15) * 128 + (((ks * 4 + quad) ^ sw) * 16));
        if (t + 2 < NT) stage(W, tileN, (t + 2) * 64, cur + 32768);
        __builtin_amdgcn_sched_barrier(0);
        __builtin_amdgcn_s_barrier();
        asm volatile("s_waitcnt lgkmcnt(0)" ::: "memory");
        __builtin_amdgcn_sched_barrier(0);
        __builtin_amdgcn_s_setprio(1);
#pragma unroll
        for (int i = 0; i < 4; ++i)
#pragma unroll
            for (int j = 0; j < 2; ++j)
#pragma unroll
                for (int ks = 0; ks < 2; ++ks)
                    acc[4 + i][2 + j] = __builtin_amdgcn_mfma_f32_16x16x32_bf16(af[i][ks], bfr[2 + j][ks], acc[4 + i][2 + j], 0, 0, 0);
        __builtin_amdgcn_s_setprio(0);
        __builtin_amdgcn_s_barrier();

        // ---- phase 4: quadrant (1,0).  Stage B-h1(t+2) -> cur.  K-tile
        //      boundary wait: vmcnt(4) (= B(t+2) halves in flight), never 0. ----
        if (t + 2 < NT) stage(W, tileN + 128, (t + 2) * 64, cur + 49152);
        __builtin_amdgcn_sched_barrier(0);
        __builtin_amdgcn_s_barrier();
        __builtin_amdgcn_s_setprio(1);
#pragma unroll
        for (int i = 0; i < 4; ++i)
#pragma unroll
            for (int j = 0; j < 2; ++j)
#pragma unroll
                for (int ks = 0; ks < 2; ++ks)
                    acc[4 + i][j] = __builtin_amdgcn_mfma_f32_16x16x32_bf16(af[i][ks], bfr[j][ks], acc[4 + i][j], 0, 0, 0);
        __builtin_amdgcn_s_setprio(0);
        if (t + 2 < NT) {
            asm volatile("s_waitcnt vmcnt(4)" ::: "memory");
        } else if (t + 1 < NT) {
            asm volatile("s_waitcnt vmcnt(0)" ::: "memory");
        }
        __builtin_amdgcn_s_barrier();
    }

    // ---- epilogue: all 4 gates of h are in this lane's acc[i][0..3][v].
    //      C/D map: col (=n, gate-fragment) = lane&15, row = quad*4 + v. ----
    const int hidx = tileN / 4 + wn * 16 + l15;       // global h in [0,1024)
    const float bi  = bx[hidx]        + bh[hidx];
    const float bff = bx[1024 + hidx] + bh[1024 + hidx];
    const float bo  = bx[2048 + hidx] + bh[2048 + hidx];
    const float bc  = bx[3072 + hidx] + bh[3072 + hidx];

#pragma unroll
    for (int i = 0; i < 8; ++i) {
#pragma unroll
        for (int v = 0; v < 4; ++v) {
            int m = wm * 128 + i * 16 + quad * 4 + v;
            size_t goff = (size_t)(tileM + m) * 1024 + hidx;
            float gi = acc[i][0][v] + bi;
            float gf = acc[i][1][v] + bff;
            float go = acc[i][2][v] + bo;
            float gc = acc[i][3][v] + bc;
            float c1v = c1[goff];
            float ii = sigmoidf_fast(gi);
            float ff = sigmoidf_fast(gf);
            float oo = sigmoidf_fast(go);
            float cb = tanhf_fast(gc);
            float cc = sigmoidf_fast(ff * c1v + ii * cb);   // reference quirk
            float hn = tanhf_fast(cc) * oo;
            out[goff] = hn;
            out[8388608 + goff] = cc;
        }
    }
}

extern "C" void kernel_launch(void* const* d_in, const int* in_sizes, int n_in,
                              void* d_out, int out_size, void* d_ws, size_t ws_size,
                              hipStream_t stream) {
    const float* x  = (const float*)d_in[0];
    const float* h  = (const float*)d_in[1];
    const float* c1 = (const float*)d_in[2];
    const float* Wx = (const float*)d_in[3];
    const float* bx = (const float*)d_in[4];
    const float* Wh = (const float*)d_in[5];
    const float* bh = (const float*)d_in[6];
    float* out = (float*)d_out;

    char* ws = (char*)d_ws;
    unsigned short* Abf = (unsigned short*)(ws);                // 33,554,432 B
    unsigned short* Wbf = (unsigned short*)(ws + 33554432);     // 16,777,216 B

    prep_cat<<<12288, 256, 0, stream>>>(x, h, Wx, Wh, Abf, Wbf);
    gemm_lstm<<<512, 512, 0, stream>>>(Abf, Wbf, bx, bh, c1, out);
}